// Round 6
// baseline (197.358 us; speedup 1.0000x reference)
//
#include <hip/hip_runtime.h>
#include <hip/hip_bf16.h>
#include <math.h>

typedef __bf16 bf16x8 __attribute__((ext_vector_type(8)));
typedef __bf16 bf16x4 __attribute__((ext_vector_type(4)));
typedef float f32x4 __attribute__((ext_vector_type(4)));

#define MFMA_BF16 __builtin_amdgcn_mfma_f32_16x16x32_bf16

// softmax scale 1/8 folded with log2(e): sv = (q.k)/8*log2e, p = exp2(sv)
#define QSCALE 0.18033688011112042f

__device__ inline void async_load16(const __hip_bfloat16* g, __hip_bfloat16* l) {
    __builtin_amdgcn_global_load_lds(
        (const __attribute__((address_space(1))) unsigned int*)g,
        (__attribute__((address_space(3))) unsigned int*)l,
        16, 0, 0);
}

// swap bits 2<->3 (row permutation for K staging; involution)
__device__ inline int sig(int x) {
    return (x & ~12) | ((x & 4) << 1) | ((x & 8) >> 1);
}

// pack two f32 into (bf16(lo), bf16(hi)) dword by truncation — 1 v_perm_b32
__device__ inline unsigned int pack_bf16_trunc(float lo, float hi) {
    return __builtin_amdgcn_perm(__float_as_uint(hi), __float_as_uint(lo),
                                 0x07060302u);
}

// ---------- one-shot fp32->bf16 for x and the 4 weight matrices ----------
__global__ __launch_bounds__(256) void convert_all(
    const float* __restrict__ x,
    const float* __restrict__ Wq, const float* __restrict__ Wk,
    const float* __restrict__ Wv, const float* __restrict__ Wp,
    __hip_bfloat16* __restrict__ xb,
    __hip_bfloat16* __restrict__ Wqb, __hip_bfloat16* __restrict__ Wkb,
    __hip_bfloat16* __restrict__ Wvb, __hip_bfloat16* __restrict__ Wpb,
    int nx, int nw)
{
    const int xblocks = nx >> 11;   // /(256*8)
    const int wblocks = nw >> 11;
    int b = blockIdx.x;
    const float* in;
    __hip_bfloat16* out;
    int i;
    if (b < xblocks) {
        in = x; out = xb; i = (b * 256 + threadIdx.x) * 8;
    } else {
        b -= xblocks;
        const int w = b / wblocks, bb = b - w * wblocks;
        in  = w == 0 ? Wq : w == 1 ? Wk : w == 2 ? Wv : Wp;
        out = w == 0 ? Wqb : w == 1 ? Wkb : w == 2 ? Wvb : Wpb;
        i = (bb * 256 + threadIdx.x) * 8;
    }
    const float4 a = *(const float4*)(in + i);
    const float4 c = *(const float4*)(in + i + 4);
    __hip_bfloat16 tmp[8];
    tmp[0] = __float2bfloat16(a.x); tmp[1] = __float2bfloat16(a.y);
    tmp[2] = __float2bfloat16(a.z); tmp[3] = __float2bfloat16(a.w);
    tmp[4] = __float2bfloat16(c.x); tmp[5] = __float2bfloat16(c.y);
    tmp[6] = __float2bfloat16(c.z); tmp[7] = __float2bfloat16(c.w);
    *(bf16x8*)(out + i) = *(const bf16x8*)tmp;
}

// ---------------- fused QKV GEMM, BK=64, swizzled LDS ----------------
// R4 (verified: ~45.8 -> ~33us): double-buffered LDS + stage-after-barrier +
// vmcnt(0) drain-before-barrier; 512 threads / 8 waves (wave tile 32x64).
// sel==2 (V) blocks transpose their 128x128 output tile through LDS and
// write V^T (C x M) directly — no separate transpose kernel.
__global__ __launch_bounds__(512) void gemm_qkv(
    const __hip_bfloat16* __restrict__ A,
    const __hip_bfloat16* __restrict__ B,
    const float* __restrict__ bq, const float* __restrict__ bk, const float* __restrict__ bv,
    __hip_bfloat16* __restrict__ Qo, __hip_bfloat16* __restrict__ Ko,
    __hip_bfloat16* __restrict__ Vt,
    int M, int K)
{
    __shared__ __align__(16) __hip_bfloat16 smem[2][2 * 128 * 64];  // [buf][A|B]

    const int tid  = threadIdx.x;       // 0..511
    const int lane = tid & 63;
    const int wave = tid >> 6;          // 0..7
    const int l15  = lane & 15;
    const int quad = lane >> 4;
    const int m0 = blockIdx.x * 128;
    const int n0 = blockIdx.y * 128;
    const int wr = wave >> 1;           // 0..3 : 32-row chunk
    const int wc = wave & 1;            // 0..1 : 64-col chunk
    const int sel = n0 >> 10;           // 0=Q 1=K 2=V, block-uniform

    f32x4 acc[2][4] = {};

    // staging map: per matrix 1024 chunks of 8 elems; 512 threads x 2
    int srow[2], scol[2];
    #pragma unroll
    for (int i = 0; i < 2; ++i) {
        const int c = tid + 512 * i;
        srow[i] = c >> 3;
        scol[i] = ((c & 7) ^ (srow[i] & 7)) * 8;
    }

    auto stageg = [&](int k0, int buf) {
        __hip_bfloat16* As = smem[buf];
        __hip_bfloat16* Bs = smem[buf] + 128 * 64;
        #pragma unroll
        for (int i = 0; i < 2; ++i) {
            async_load16(A + (size_t)(m0 + srow[i]) * K + k0 + scol[i],
                         As + (size_t)(tid + 512 * i) * 8);
            async_load16(B + (size_t)(n0 + srow[i]) * K + k0 + scol[i],
                         Bs + (size_t)(tid + 512 * i) * 8);
        }
    };

    const int NK = K >> 6;   // 16
    stageg(0, 0);

    for (int kt = 0; kt < NK; ++kt) {
        // drain stage(kt) (only thing in flight), then barrier
        asm volatile("s_waitcnt vmcnt(0)\n\ts_barrier" ::: "memory");
        if (kt + 1 < NK) stageg((kt + 1) * 64, (kt + 1) & 1);

        const __hip_bfloat16* As = smem[kt & 1];
        const __hip_bfloat16* Bs = smem[kt & 1] + 128 * 64;

        #pragma unroll
        for (int kd = 0; kd < 2; ++kd) {
            bf16x8 af[2], bfr[4];
            #pragma unroll
            for (int mi = 0; mi < 2; ++mi) {
                const int row = wr * 32 + mi * 16 + l15;
                af[mi] = *(const bf16x8*)(
                    As + row * 64 + (((kd * 4 + quad) ^ (row & 7)) << 3));
            }
            #pragma unroll
            for (int ni = 0; ni < 4; ++ni) {
                const int row = wc * 64 + ni * 16 + l15;
                bfr[ni] = *(const bf16x8*)(
                    Bs + row * 64 + (((kd * 4 + quad) ^ (row & 7)) << 3));
            }
            #pragma unroll
            for (int mi = 0; mi < 2; ++mi)
                #pragma unroll
                for (int ni = 0; ni < 4; ++ni)
                    acc[mi][ni] = MFMA_BF16(af[mi], bfr[ni], acc[mi][ni], 0, 0, 0);
        }
    }

    if (sel == 2) {
        // ---- V: transpose 128x128 tile through LDS, write V^T coalesced ----
        __hip_bfloat16* tsm = smem[0];
        __syncthreads();
        #pragma unroll
        for (int ni = 0; ni < 4; ++ni) {
            const int lc = wc * 64 + ni * 16 + l15;        // local channel
            const float bias = bv[(n0 + lc) & 1023];
            #pragma unroll
            for (int mi = 0; mi < 2; ++mi) {
                const int mb = wr * 32 + mi * 16 + quad * 4;   // local token base
                const int g = mb >> 3, off = mb & 7;
                __hip_bfloat16 t[4];
                #pragma unroll
                for (int r = 0; r < 4; ++r)
                    t[r] = __float2bfloat16(acc[mi][ni][r] + bias);
                *(bf16x4*)(tsm + lc * 128 + ((g ^ (lc & 15)) << 3) + off)
                    = *(const bf16x4*)t;
            }
        }
        __syncthreads();
        const int cc0 = n0 & 1023;
        #pragma unroll
        for (int i = 0; i < 4; ++i) {
            const int q = tid + 512 * i;          // 2048 16B chunks
            const int ch = q >> 4, mg = q & 15;
            bf16x8 v = *(const bf16x8*)(tsm + ch * 128 + ((mg ^ (ch & 15)) << 3));
            *(bf16x8*)(Vt + (size_t)(cc0 + ch) * M + m0 + mg * 8) = v;
        }
    } else {
        __hip_bfloat16* dst = sel == 0 ? Qo : Ko;
        const float* bptr   = sel == 0 ? bq : bk;
        const float sc      = sel == 0 ? QSCALE : 1.0f;
        #pragma unroll
        for (int ni = 0; ni < 4; ++ni) {
            const int cc = (n0 + wc * 64 + ni * 16 + l15) & 1023;
            const float bias = bptr[cc];
            #pragma unroll
            for (int mi = 0; mi < 2; ++mi) {
                const int row = m0 + wr * 32 + mi * 16 + quad * 4;
                #pragma unroll
                for (int r = 0; r < 4; ++r)
                    dst[(size_t)(row + r) * 1024 + cc] =
                        __float2bfloat16((acc[mi][ni][r] + bias) * sc);
            }
        }
    }
}

// ---------------- out-proj GEMM (fp32 out), 64x128 tile, BK=64 ----------------
// Same dbuf + stage-after-barrier structure as gemm_qkv.
__global__ __launch_bounds__(256) void gemm_out_f32(
    const __hip_bfloat16* __restrict__ A,
    const __hip_bfloat16* __restrict__ B,
    const float* __restrict__ bias,
    float* __restrict__ Cf,
    int M, int N, int K)
{
    __shared__ __align__(16) __hip_bfloat16 smem[2][(64 + 128) * 64];  // [buf][A|B]

    const int tid  = threadIdx.x;
    const int lane = tid & 63;
    const int wave = tid >> 6;
    const int l15  = lane & 15;
    const int quad = lane >> 4;
    const int m0 = blockIdx.x * 64;
    const int n0 = blockIdx.y * 128;
    const int wr = wave >> 1, wc = wave & 1;   // wave tile: 32 x 64

    f32x4 acc[2][4] = {};

    int srow[4], scol[4];
    #pragma unroll
    for (int i = 0; i < 4; ++i) {
        const int c = tid + 256 * i;
        srow[i] = c >> 3;
        scol[i] = ((c & 7) ^ (srow[i] & 7)) * 8;
    }

    auto stageg = [&](int k0, int buf) {
        __hip_bfloat16* As = smem[buf];
        __hip_bfloat16* Bs = smem[buf] + 64 * 64;
        #pragma unroll
        for (int i = 0; i < 2; ++i)
            async_load16(A + (size_t)(m0 + srow[i]) * K + k0 + scol[i],
                         As + (size_t)(tid + 256 * i) * 8);
        #pragma unroll
        for (int i = 0; i < 4; ++i)
            async_load16(B + (size_t)(n0 + srow[i]) * K + k0 + scol[i],
                         Bs + (size_t)(tid + 256 * i) * 8);
    };

    const int NK = K >> 6;   // 16
    stageg(0, 0);

    for (int kt = 0; kt < NK; ++kt) {
        asm volatile("s_waitcnt vmcnt(0)\n\ts_barrier" ::: "memory");
        if (kt + 1 < NK) stageg((kt + 1) * 64, (kt + 1) & 1);

        const __hip_bfloat16* As = smem[kt & 1];
        const __hip_bfloat16* Bs = smem[kt & 1] + 64 * 64;

        #pragma unroll
        for (int kd = 0; kd < 2; ++kd) {
            bf16x8 af[2], bfr[4];
            #pragma unroll
            for (int mi = 0; mi < 2; ++mi) {
                const int row = wr * 32 + mi * 16 + l15;
                af[mi] = *(const bf16x8*)(
                    As + row * 64 + (((kd * 4 + quad) ^ (row & 7)) << 3));
            }
            #pragma unroll
            for (int ni = 0; ni < 4; ++ni) {
                const int row = wc * 64 + ni * 16 + l15;
                bfr[ni] = *(const bf16x8*)(
                    Bs + row * 64 + (((kd * 4 + quad) ^ (row & 7)) << 3));
            }
            #pragma unroll
            for (int mi = 0; mi < 2; ++mi)
                #pragma unroll
                for (int ni = 0; ni < 4; ++ni)
                    acc[mi][ni] = MFMA_BF16(af[mi], bfr[ni], acc[mi][ni], 0, 0, 0);
        }
    }

    #pragma unroll
    for (int ni = 0; ni < 4; ++ni) {
        const int col = n0 + wc * 64 + ni * 16 + l15;
        const float bv = bias[col];
        #pragma unroll
        for (int mi = 0; mi < 2; ++mi) {
            const int row = m0 + wr * 32 + mi * 16 + quad * 4;
            #pragma unroll
            for (int r = 0; r < 4; ++r)
                Cf[(size_t)(row + r) * N + col] = acc[mi][ni][r] + bv;
        }
    }
}

// ---------------- flash attention: balanced pair + quarter-split ----------------
// 256-row q-tiles (16 tiles). Block = (pair j, quarter s, head h): runs tile j's
// quarter-s key range (j+1 iters) then tile (15-j)'s quarter-s range (16-j iters)
// sequentially — exactly 17 iters per block, perfectly uniform grid.
// 8 waves x 32 q-rows; 64-key blocks.
//
// R3 (verified): depth-2 prefetch 4-slot LDS ring + counted-vmcnt barrier +
// bijective XCD-chunked remap (FETCH 71.9->12.6MB). R5's 2-iter phases were
// NULL (46.9 vs 45.3) -> reverted to the R3 1-iter loop.
//
// R6 (this round): INTER-BLOCK PHASE STAGGER. Each CU hosts exactly 2 blocks
// with identical iteration structure launched simultaneously -> they run
// phase-LOCKED: both burst MFMA (QK+PV) together while VALU idles, then both
// do softmax together while the matrix pipe idles (measured MfmaUtil~33 =
// VALUBusy~33, period ~6600cyc vs ~2800 matrix + ~2200 VALU demand). The two
// blocks are independent (separate barriers) — offsetting one by ~half an
// iteration (2x s_sleep 15 ~ 1900cyc, by PHYSICAL linear id >= 256 = the
// second dispatch fill) lets block A's softmax overlap block B's MFMA for the
// whole kernel (identical per-iter durations preserve the offset).
// Plus T5 s_setprio(1) around MFMA clusters (m191: +4-7% attn once waves are
// at different phases). Sleep is correctness-free; no inter-block deps.
//
// S^T = K.Q^T with key labeling key(sb,m)=32(sb&1)+8(m>>2)+4(sb>>1)+(m&3) so the
// S^T C-layout regs ARE the P B-frags for O^T = V^T.P^T (P never leaves regs).
// Partials (unnormalized bf16 O, fp32 l) written per quarter; merged by merge_y.
// NO device-scope fences/atomics in-kernel: R9 showed __threadfence() costs ~8x.
__global__ __launch_bounds__(512, 4) void attn_causal(
    const __hip_bfloat16* __restrict__ Q,
    const __hip_bfloat16* __restrict__ K,
    const __hip_bfloat16* __restrict__ Vt,
    __hip_bfloat16* __restrict__ PoB,   // [4][T*C]
    float* __restrict__ PlB,            // [4][16*T]
    int T, int C)
{
    // physical linear id (pre-remap) — co-residency is physical:
    // blocks 0..255 fill slot 0 on each CU, 256..511 fill slot 1.
    const int plin = (int)(blockIdx.x + gridDim.x * blockIdx.y);
    if (plin & 256)
        asm volatile("s_sleep 15\n\ts_sleep 15" :::);

    // XCD-aware remap: lin -> (xcd chunk) so heads pair up per XCD.
    const int nwg  = (int)(gridDim.x * gridDim.y);      // 512
    const int chunk = nwg >> 3;                          // 64 (nwg % 8 == 0)
    const int work = (plin & 7) * chunk + (plin >> 3);
    const int h  = work >> 5;           // head [0,16)
    const int bx = work & 31;           // [0,32)
    const int j  = bx & 7;              // pair index
    const int sq = bx >> 3;             // quarter [0,4)
    const int tid  = threadIdx.x;
    const int w    = tid >> 6;          // wave [0,8)
    const int lane = tid & 63;
    const int l15  = lane & 15;
    const int quad = lane >> 4;

    const size_t TCs = (size_t)T * C;
    const size_t HT  = (size_t)T * 16;
    __hip_bfloat16* Po = PoB + (size_t)sq * TCs;
    float* Pl = PlB + (size_t)sq * HT;

    const int len1 = j + 1, len2 = 16 - j;
    const int tile1 = j,    tile2 = 15 - j;
    const int kb1 = len1 * sq, kb2 = len2 * sq;   // quarter starts

    __shared__ __align__(16) __hip_bfloat16 Ks[4][64 * 64];
    __shared__ __align__(16) __hip_bfloat16 Vts[4][64 * 64];

    const int r0 = tid >> 3, g0 = ((tid & 7) ^ (r0 & 7)) * 8;
    const __hip_bfloat16* Kg0 = K + (size_t)sig(r0) * C + h * 64 + g0;
    const __hip_bfloat16* Vg0 = Vt + (size_t)(h * 64 + r0) * T + g0;

    int koff[2][4], voff[2][4];
    #pragma unroll
    for (int kd = 0; kd < 2; ++kd)
        #pragma unroll
        for (int sb = 0; sb < 4; ++sb) {
            const int kappa = 32 * (sb & 1) + 8 * (l15 >> 2) + 4 * (sb >> 1) + (l15 & 3);
            const int rho = sig(kappa);
            koff[kd][sb] = rho * 64 + (((kd * 4 + quad) ^ (rho & 7)) << 3);
        }
    #pragma unroll
    for (int kk = 0; kk < 2; ++kk)
        #pragma unroll
        for (int db = 0; db < 4; ++db) {
            const int vrow = db * 16 + l15;
            voff[kk][db] = vrow * 64 + (((kk * 4 + quad) ^ (vrow & 7)) << 3);
        }

    bf16x8 ones;
    #pragma unroll
    for (int jj = 0; jj < 8; ++jj) ones[jj] = (__bf16)1.0f;

    int qbase = tile1 * 256 + w * 32;
    // aq loads issued BEFORE the stages: vmcnt retires in order, so the
    // compiler's wait-for-aq never forces the (newer) prefetch to drain.
    bf16x8 aq[2][2];
    #pragma unroll
    for (int rb = 0; rb < 2; ++rb)
        #pragma unroll
        for (int kd = 0; kd < 2; ++kd)
            aq[rb][kd] = *(const bf16x8*)(
                Q + (size_t)(qbase + rb * 16 + l15) * C + h * 64 + kd * 32 + quad * 8);

    f32x4 o[2][4] = {};
    f32x4 lacc[2] = {};

    // stage K/V chunk for flattened index idx into ring slot idx&3 (2 loads)
    auto stage = [&](int idx) {
        const int kb = (idx < len1) ? (kb1 + idx) : (kb2 + idx - len1);
        const size_t so = (size_t)kb << 6;
        const int sl = idx & 3;
        async_load16(Kg0 + so * C, &Ks[sl][tid * 8]);
        async_load16(Vg0 + so, &Vts[sl][tid * 8]);
    };

    stage(0);
    stage(1);

    for (int it = 0; it < 17; ++it) {
        if (it + 2 < 17) stage(it + 2);
        // counted-vmcnt barrier: wait only for stage(it) (oldest 2 loads),
        // leaving the 4 prefetch loads for it+1/it+2 in flight across the
        // barrier. Every wave does the same wait before s_barrier, so after
        // the barrier slot it&3 is fully populated by all 512 threads.
        if (it < 15)
            asm volatile("s_waitcnt vmcnt(4)\n\ts_barrier" ::: "memory");
        else if (it == 15)
            asm volatile("s_waitcnt vmcnt(2)\n\ts_barrier" ::: "memory");
        else
            asm volatile("s_waitcnt vmcnt(0)\n\ts_barrier" ::: "memory");

        const int cur = it & 3;
        const int kb = (it < len1) ? (kb1 + it) : (kb2 + it - len1);
        const int s0 = kb << 6;

        if (it == len1) {
            // flush phase-1 partials, switch to tile2
            #pragma unroll
            for (int rb = 0; rb < 2; ++rb) {
                const int row = qbase + rb * 16 + l15;
                #pragma unroll
                for (int db = 0; db < 4; ++db) {
                    __hip_bfloat16 t[4];
                    #pragma unroll
                    for (int r = 0; r < 4; ++r)
                        t[r] = __float2bfloat16(o[rb][db][r]);
                    *(bf16x4*)(Po + (size_t)row * C + h * 64 + db * 16 + quad * 4)
                        = *(const bf16x4*)t;
                    o[rb][db] = (f32x4){0.f, 0.f, 0.f, 0.f};
                }
                if (quad == 0)
                    Pl[(size_t)h * T + row] = lacc[rb][0];
                lacc[rb] = (f32x4){0.f, 0.f, 0.f, 0.f};
            }
            qbase = tile2 * 256 + w * 32;
            #pragma unroll
            for (int rb = 0; rb < 2; ++rb)
                #pragma unroll
                for (int kd = 0; kd < 2; ++kd)
                    aq[rb][kd] = *(const bf16x8*)(
                        Q + (size_t)(qbase + rb * 16 + l15) * C + h * 64 + kd * 32 + quad * 8);
        }

        if (s0 <= qbase + 31) {   // wave-uniform skip
            __builtin_amdgcn_s_setprio(1);
            f32x4 sv[2][4] = {};
            #pragma unroll
            for (int kd = 0; kd < 2; ++kd)
                #pragma unroll
                for (int sb = 0; sb < 4; ++sb) {
                    bf16x8 ak = *(const bf16x8*)(&Ks[cur][koff[kd][sb]]);
                    sv[0][sb] = MFMA_BF16(ak, aq[0][kd], sv[0][sb], 0, 0, 0);
                    sv[1][sb] = MFMA_BF16(ak, aq[1][kd], sv[1][sb], 0, 0, 0);
                }
            __builtin_amdgcn_s_setprio(0);

            const bool diag = (s0 + 63 > qbase);  // wave-uniform
            bf16x8 bp[2][2];
            #pragma unroll
            for (int rb = 0; rb < 2; ++rb) {
                float pv[4][4];
                #pragma unroll
                for (int sb = 0; sb < 4; ++sb)
                    #pragma unroll
                    for (int r = 0; r < 4; ++r)
                        pv[sb][r] = __builtin_amdgcn_exp2f(sv[rb][sb][r]);
                if (diag) {
                    const int thr = qbase + rb * 16 + l15 - s0 - 8 * quad;
                    #pragma unroll
                    for (int sb = 0; sb < 4; ++sb)
                        #pragma unroll
                        for (int r = 0; r < 4; ++r) {
                            const int c = 32 * (sb & 1) + 4 * (sb >> 1) + r;
                            pv[sb][r] = (c <= thr) ? pv[sb][r] : 0.f;
                        }
                }
                #pragma unroll
                for (int kk = 0; kk < 2; ++kk) {
                    union { unsigned int u[4]; bf16x8 v; } pk;
                    pk.u[0] = pack_bf16_trunc(pv[kk][0], pv[kk][1]);
                    pk.u[1] = pack_bf16_trunc(pv[kk][2], pv[kk][3]);
                    pk.u[2] = pack_bf16_trunc(pv[kk + 2][0], pv[kk + 2][1]);
                    pk.u[3] = pack_bf16_trunc(pv[kk + 2][2], pv[kk + 2][3]);
                    bp[rb][kk] = pk.v;
                }
            }

            __builtin_amdgcn_s_setprio(1);
            // l += 1^T . P^T  (matrix pipe)
            lacc[0] = MFMA_BF16(ones, bp[0][0], lacc[0], 0, 0, 0);
            lacc[0] = MFMA_BF16(ones, bp[0][1], lacc[0], 0, 0, 0);
            lacc[1] = MFMA_BF16(ones, bp[1][0], lacc[1], 0, 0, 0);
            lacc[1] = MFMA_BF16(ones, bp[1][1], lacc[1], 0, 0, 0);

            // O^T += V^T . P^T
            #pragma unroll
            for (int kk = 0; kk < 2; ++kk)
                #pragma unroll
                for (int db = 0; db < 4; ++db) {
                    bf16x8 av = *(const bf16x8*)(&Vts[cur][voff[kk][db]]);
                    o[0][db] = MFMA_BF16(av, bp[0][kk], o[0][db], 0, 0, 0);
                    o[1][db] = MFMA_BF16(av, bp[1][kk], o[1][db], 0, 0, 0);
                }
            __builtin_amdgcn_s_setprio(0);
        }
    }

    // final flush (tile2)
    #pragma unroll
    for (int rb = 0; rb < 2; ++rb) {
        const int row = qbase + rb * 16 + l15;
        #pragma unroll
        for (int db = 0; db < 4; ++db) {
            __hip_bfloat16 t[4];
            #pragma unroll
            for (int r = 0; r < 4; ++r)
                t[r] = __float2bfloat16(o[rb][db][r]);
            *(bf16x4*)(Po + (size_t)row * C + h * 64 + db * 16 + quad * 4)
                = *(const bf16x4*)t;
        }
        if (quad == 0)
            Pl[(size_t)h * T + row] = lacc[rb][0];
    }
}

// Y = (sum_z Po[z]) / (sum_z Pl[z]), bf16 out. 8 elems/thread.
__global__ __launch_bounds__(256) void merge_y(
    const __hip_bfloat16* __restrict__ PoB, const float* __restrict__ PlB,
    __hip_bfloat16* __restrict__ Y, int T, int C)
{
    const size_t i = ((size_t)blockIdx.x * 256 + threadIdx.x) * 8;
    const int row = (int)(i / C);
    const int h   = ((int)(i % C)) >> 6;
    const size_t TC = (size_t)T * C;
    const size_t HT = (size_t)T * 16;
    float acc[8] = {};
    float l = 0.f;
    #pragma unroll
    for (int z = 0; z < 4; ++z) {
        bf16x8 a = *(const bf16x8*)(PoB + z * TC + i);
        #pragma unroll
        for (int r = 0; r < 8; ++r)
            acc[r] += (float)(((const __bf16*)&a)[r]);
        l += PlB[z * HT + (size_t)h * T + row];
    }
    const float inv = 1.0f / l;
    __hip_bfloat16 t[8];
    #pragma unroll
    for (int r = 0; r < 8; ++r)
        t[r] = __float2bfloat16(acc[r] * inv);
    *(bf16x8*)(Y + i) = *(const bf16x8*)t;
}

extern "C" void kernel_launch(void* const* d_in, const int* in_sizes, int n_in,
                              void* d_out, int out_size, void* d_ws, size_t ws_size,
                              hipStream_t stream)
{
    const float* x  = (const float*)d_in[0];
    const float* Wq = (const float*)d_in[1];
    const float* bq = (const float*)d_in[2];
    const float* Wk = (const float*)d_in[3];
    const float* bk = (const float*)d_in[4];
    const float* Wv = (const float*)d_in[5];
    const float* bv = (const float*)d_in[6];
    const float* Wp = (const float*)d_in[7];
    const float* bp = (const float*)d_in[8];

    const int C = 1024;
    const int T = in_sizes[0] / C;   // 4096
    const int H = 16;
    const size_t TC = (size_t)T * C;
    const size_t CC = (size_t)C * C;

    // ws (bf16 elems): xb | W4 | Q | K | Vt | Po[4] | Pl[4] (f32)
    __hip_bfloat16* xb  = (__hip_bfloat16*)d_ws;
    __hip_bfloat16* Wqb = xb + TC;
    __hip_bfloat16* Wkb = Wqb + CC;
    __hip_bfloat16* Wvb = Wkb + CC;
    __hip_bfloat16* Wpb = Wvb + CC;
    __hip_bfloat16* Qw  = Wpb + CC;
    __hip_bfloat16* Kw  = Qw + TC;
    __hip_bfloat16* Vtw = Kw + TC;
    __hip_bfloat16* PoB = Vtw + TC;          // 4 * TC bf16
    float* PlB = (float*)(PoB + 4 * TC);     // 4 * 16*T fp32
    __hip_bfloat16* Yw  = xb;                // alias: x dead after QKV GEMM
    float* out = (float*)d_out;

    convert_all<<<(int)(TC / 2048 + 4 * CC / 2048), 256, 0, stream>>>(
        x, Wq, Wk, Wv, Wp, xb, Wqb, Wkb, Wvb, Wpb, (int)TC, (int)CC);

    gemm_qkv<<<dim3(T / 128, 3072 / 128), 512, 0, stream>>>(
        xb, Wqb, bq, bk, bv, Qw, Kw, Vtw, T, C);

    attn_causal<<<dim3(32, H), 512, 0, stream>>>(
        Qw, Kw, Vtw, PoB, PlB, T, C);

    merge_y<<<(int)(TC / 8 / 256), 256, 0, stream>>>(
        PoB, PlB, Yw, T, C);

    gemm_out_f32<<<dim3(T / 64, C / 128), 256, 0, stream>>>(
        Yw, Wpb, bp, out, T, C, C);
}

// Round 7
// 180.148 us; speedup vs baseline: 1.0955x; 1.0955x over previous
//
#include <hip/hip_runtime.h>
#include <hip/hip_bf16.h>
#include <math.h>

typedef __bf16 bf16x8 __attribute__((ext_vector_type(8)));
typedef __bf16 bf16x4 __attribute__((ext_vector_type(4)));
typedef float f32x4 __attribute__((ext_vector_type(4)));

#define MFMA_BF16 __builtin_amdgcn_mfma_f32_16x16x32_bf16

// softmax scale 1/8 folded with log2(e): sv = (q.k)/8*log2e, p = exp2(sv)
#define QSCALE 0.18033688011112042f

__device__ inline void async_load16(const __hip_bfloat16* g, __hip_bfloat16* l) {
    __builtin_amdgcn_global_load_lds(
        (const __attribute__((address_space(1))) unsigned int*)g,
        (__attribute__((address_space(3))) unsigned int*)l,
        16, 0, 0);
}

// swap bits 2<->3 (row permutation for K staging; involution)
__device__ inline int sig(int x) {
    return (x & ~12) | ((x & 4) << 1) | ((x & 8) >> 1);
}

// pack two f32 into (bf16(lo), bf16(hi)) dword by truncation — 1 v_perm_b32
__device__ inline unsigned int pack_bf16_trunc(float lo, float hi) {
    return __builtin_amdgcn_perm(__float_as_uint(hi), __float_as_uint(lo),
                                 0x07060302u);
}

// ---------- one-shot fp32->bf16 for x and the 4 weight matrices ----------
__global__ __launch_bounds__(256) void convert_all(
    const float* __restrict__ x,
    const float* __restrict__ Wq, const float* __restrict__ Wk,
    const float* __restrict__ Wv, const float* __restrict__ Wp,
    __hip_bfloat16* __restrict__ xb,
    __hip_bfloat16* __restrict__ Wqb, __hip_bfloat16* __restrict__ Wkb,
    __hip_bfloat16* __restrict__ Wvb, __hip_bfloat16* __restrict__ Wpb,
    int nx, int nw)
{
    const int xblocks = nx >> 11;   // /(256*8)
    const int wblocks = nw >> 11;
    int b = blockIdx.x;
    const float* in;
    __hip_bfloat16* out;
    int i;
    if (b < xblocks) {
        in = x; out = xb; i = (b * 256 + threadIdx.x) * 8;
    } else {
        b -= xblocks;
        const int w = b / wblocks, bb = b - w * wblocks;
        in  = w == 0 ? Wq : w == 1 ? Wk : w == 2 ? Wv : Wp;
        out = w == 0 ? Wqb : w == 1 ? Wkb : w == 2 ? Wvb : Wpb;
        i = (bb * 256 + threadIdx.x) * 8;
    }
    const float4 a = *(const float4*)(in + i);
    const float4 c = *(const float4*)(in + i + 4);
    __hip_bfloat16 tmp[8];
    tmp[0] = __float2bfloat16(a.x); tmp[1] = __float2bfloat16(a.y);
    tmp[2] = __float2bfloat16(a.z); tmp[3] = __float2bfloat16(a.w);
    tmp[4] = __float2bfloat16(c.x); tmp[5] = __float2bfloat16(c.y);
    tmp[6] = __float2bfloat16(c.z); tmp[7] = __float2bfloat16(c.w);
    *(bf16x8*)(out + i) = *(const bf16x8*)tmp;
}

// ---------------- fused QKV GEMM, BK=64, swizzled LDS ----------------
// R4 (verified: ~45.8 -> ~33us): double-buffered LDS + stage-after-barrier +
// vmcnt(0) drain-before-barrier; 512 threads / 8 waves (wave tile 32x64).
// sel==2 (V) blocks transpose their 128x128 output tile through LDS and
// write V^T (C x M) directly — no separate transpose kernel.
__global__ __launch_bounds__(512) void gemm_qkv(
    const __hip_bfloat16* __restrict__ A,
    const __hip_bfloat16* __restrict__ B,
    const float* __restrict__ bq, const float* __restrict__ bk, const float* __restrict__ bv,
    __hip_bfloat16* __restrict__ Qo, __hip_bfloat16* __restrict__ Ko,
    __hip_bfloat16* __restrict__ Vt,
    int M, int K)
{
    __shared__ __align__(16) __hip_bfloat16 smem[2][2 * 128 * 64];  // [buf][A|B]

    const int tid  = threadIdx.x;       // 0..511
    const int lane = tid & 63;
    const int wave = tid >> 6;          // 0..7
    const int l15  = lane & 15;
    const int quad = lane >> 4;
    const int m0 = blockIdx.x * 128;
    const int n0 = blockIdx.y * 128;
    const int wr = wave >> 1;           // 0..3 : 32-row chunk
    const int wc = wave & 1;            // 0..1 : 64-col chunk
    const int sel = n0 >> 10;           // 0=Q 1=K 2=V, block-uniform

    f32x4 acc[2][4] = {};

    // staging map: per matrix 1024 chunks of 8 elems; 512 threads x 2
    int srow[2], scol[2];
    #pragma unroll
    for (int i = 0; i < 2; ++i) {
        const int c = tid + 512 * i;
        srow[i] = c >> 3;
        scol[i] = ((c & 7) ^ (srow[i] & 7)) * 8;
    }

    auto stageg = [&](int k0, int buf) {
        __hip_bfloat16* As = smem[buf];
        __hip_bfloat16* Bs = smem[buf] + 128 * 64;
        #pragma unroll
        for (int i = 0; i < 2; ++i) {
            async_load16(A + (size_t)(m0 + srow[i]) * K + k0 + scol[i],
                         As + (size_t)(tid + 512 * i) * 8);
            async_load16(B + (size_t)(n0 + srow[i]) * K + k0 + scol[i],
                         Bs + (size_t)(tid + 512 * i) * 8);
        }
    };

    const int NK = K >> 6;   // 16
    stageg(0, 0);

    for (int kt = 0; kt < NK; ++kt) {
        // drain stage(kt) (only thing in flight), then barrier
        asm volatile("s_waitcnt vmcnt(0)\n\ts_barrier" ::: "memory");
        if (kt + 1 < NK) stageg((kt + 1) * 64, (kt + 1) & 1);

        const __hip_bfloat16* As = smem[kt & 1];
        const __hip_bfloat16* Bs = smem[kt & 1] + 128 * 64;

        #pragma unroll
        for (int kd = 0; kd < 2; ++kd) {
            bf16x8 af[2], bfr[4];
            #pragma unroll
            for (int mi = 0; mi < 2; ++mi) {
                const int row = wr * 32 + mi * 16 + l15;
                af[mi] = *(const bf16x8*)(
                    As + row * 64 + (((kd * 4 + quad) ^ (row & 7)) << 3));
            }
            #pragma unroll
            for (int ni = 0; ni < 4; ++ni) {
                const int row = wc * 64 + ni * 16 + l15;
                bfr[ni] = *(const bf16x8*)(
                    Bs + row * 64 + (((kd * 4 + quad) ^ (row & 7)) << 3));
            }
            #pragma unroll
            for (int mi = 0; mi < 2; ++mi)
                #pragma unroll
                for (int ni = 0; ni < 4; ++ni)
                    acc[mi][ni] = MFMA_BF16(af[mi], bfr[ni], acc[mi][ni], 0, 0, 0);
        }
    }

    if (sel == 2) {
        // ---- V: transpose 128x128 tile through LDS, write V^T coalesced ----
        __hip_bfloat16* tsm = smem[0];
        __syncthreads();
        #pragma unroll
        for (int ni = 0; ni < 4; ++ni) {
            const int lc = wc * 64 + ni * 16 + l15;        // local channel
            const float bias = bv[(n0 + lc) & 1023];
            #pragma unroll
            for (int mi = 0; mi < 2; ++mi) {
                const int mb = wr * 32 + mi * 16 + quad * 4;   // local token base
                const int g = mb >> 3, off = mb & 7;
                __hip_bfloat16 t[4];
                #pragma unroll
                for (int r = 0; r < 4; ++r)
                    t[r] = __float2bfloat16(acc[mi][ni][r] + bias);
                *(bf16x4*)(tsm + lc * 128 + ((g ^ (lc & 15)) << 3) + off)
                    = *(const bf16x4*)t;
            }
        }
        __syncthreads();
        const int cc0 = n0 & 1023;
        #pragma unroll
        for (int i = 0; i < 4; ++i) {
            const int q = tid + 512 * i;          // 2048 16B chunks
            const int ch = q >> 4, mg = q & 15;
            bf16x8 v = *(const bf16x8*)(tsm + ch * 128 + ((mg ^ (ch & 15)) << 3));
            *(bf16x8*)(Vt + (size_t)(cc0 + ch) * M + m0 + mg * 8) = v;
        }
    } else {
        __hip_bfloat16* dst = sel == 0 ? Qo : Ko;
        const float* bptr   = sel == 0 ? bq : bk;
        const float sc      = sel == 0 ? QSCALE : 1.0f;
        #pragma unroll
        for (int ni = 0; ni < 4; ++ni) {
            const int cc = (n0 + wc * 64 + ni * 16 + l15) & 1023;
            const float bias = bptr[cc];
            #pragma unroll
            for (int mi = 0; mi < 2; ++mi) {
                const int row = m0 + wr * 32 + mi * 16 + quad * 4;
                #pragma unroll
                for (int r = 0; r < 4; ++r)
                    dst[(size_t)(row + r) * 1024 + cc] =
                        __float2bfloat16((acc[mi][ni][r] + bias) * sc);
            }
        }
    }
}

// ---------------- out-proj GEMM (fp32 out), 64x128 tile, BK=64 ----------------
// Same dbuf + stage-after-barrier structure as gemm_qkv.
__global__ __launch_bounds__(256) void gemm_out_f32(
    const __hip_bfloat16* __restrict__ A,
    const __hip_bfloat16* __restrict__ B,
    const float* __restrict__ bias,
    float* __restrict__ Cf,
    int M, int N, int K)
{
    __shared__ __align__(16) __hip_bfloat16 smem[2][(64 + 128) * 64];  // [buf][A|B]

    const int tid  = threadIdx.x;
    const int lane = tid & 63;
    const int wave = tid >> 6;
    const int l15  = lane & 15;
    const int quad = lane >> 4;
    const int m0 = blockIdx.x * 64;
    const int n0 = blockIdx.y * 128;
    const int wr = wave >> 1, wc = wave & 1;   // wave tile: 32 x 64

    f32x4 acc[2][4] = {};

    int srow[4], scol[4];
    #pragma unroll
    for (int i = 0; i < 4; ++i) {
        const int c = tid + 256 * i;
        srow[i] = c >> 3;
        scol[i] = ((c & 7) ^ (srow[i] & 7)) * 8;
    }

    auto stageg = [&](int k0, int buf) {
        __hip_bfloat16* As = smem[buf];
        __hip_bfloat16* Bs = smem[buf] + 64 * 64;
        #pragma unroll
        for (int i = 0; i < 2; ++i)
            async_load16(A + (size_t)(m0 + srow[i]) * K + k0 + scol[i],
                         As + (size_t)(tid + 256 * i) * 8);
        #pragma unroll
        for (int i = 0; i < 4; ++i)
            async_load16(B + (size_t)(n0 + srow[i]) * K + k0 + scol[i],
                         Bs + (size_t)(tid + 256 * i) * 8);
    };

    const int NK = K >> 6;   // 16
    stageg(0, 0);

    for (int kt = 0; kt < NK; ++kt) {
        asm volatile("s_waitcnt vmcnt(0)\n\ts_barrier" ::: "memory");
        if (kt + 1 < NK) stageg((kt + 1) * 64, (kt + 1) & 1);

        const __hip_bfloat16* As = smem[kt & 1];
        const __hip_bfloat16* Bs = smem[kt & 1] + 64 * 64;

        #pragma unroll
        for (int kd = 0; kd < 2; ++kd) {
            bf16x8 af[2], bfr[4];
            #pragma unroll
            for (int mi = 0; mi < 2; ++mi) {
                const int row = wr * 32 + mi * 16 + l15;
                af[mi] = *(const bf16x8*)(
                    As + row * 64 + (((kd * 4 + quad) ^ (row & 7)) << 3));
            }
            #pragma unroll
            for (int ni = 0; ni < 4; ++ni) {
                const int row = wc * 64 + ni * 16 + l15;
                bfr[ni] = *(const bf16x8*)(
                    Bs + row * 64 + (((kd * 4 + quad) ^ (row & 7)) << 3));
            }
            #pragma unroll
            for (int mi = 0; mi < 2; ++mi)
                #pragma unroll
                for (int ni = 0; ni < 4; ++ni)
                    acc[mi][ni] = MFMA_BF16(af[mi], bfr[ni], acc[mi][ni], 0, 0, 0);
        }
    }

    #pragma unroll
    for (int ni = 0; ni < 4; ++ni) {
        const int col = n0 + wc * 64 + ni * 16 + l15;
        const float bv = bias[col];
        #pragma unroll
        for (int mi = 0; mi < 2; ++mi) {
            const int row = m0 + wr * 32 + mi * 16 + quad * 4;
            #pragma unroll
            for (int r = 0; r < 4; ++r)
                Cf[(size_t)(row + r) * N + col] = acc[mi][ni][r] + bv;
        }
    }
}

// ---------------- flash attention: balanced pair + quarter-split ----------------
// 256-row q-tiles (16 tiles). Block = (pair j, quarter s, head h): runs tile j's
// quarter-s key range (j+1 iters) then tile (15-j)'s quarter-s range (16-j iters)
// sequentially — exactly 17 iters per block, perfectly uniform grid.
// 8 waves x 32 q-rows; 64-key blocks.
//
// R3 (verified): depth-2 prefetch 4-slot LDS ring + counted-vmcnt barrier +
// bijective XCD-chunked remap (FETCH 71.9->12.6MB).
// R5 (2-iter phases) NULL; R6 (sleep stagger + setprio) REGRESSED 45->63us
// (broke the co-XCD L2 temporal locality: FETCH/WRITE +6-7MB) — both reverted.
//
// R7 (this round): DEFERRED-PV AT 1 BLOCK/CU. R2 proved the deferred-PV
// schedule CORRECT but it spilled at __launch_bounds__(512,4) (128-VGPR cap,
// +18MB/dir scratch). Here: __launch_bounds__(512,2) -> 256-VGPR cap, one
// block/CU (2 waves/SIMD), ~150-190 live regs, no spill. Each iteration:
//   PV(it-1) [20 MFMA, indep] -> [flush@len1 + aq reload] -> QK(it) [16 MFMA]
//   -> softmax(it) -> bp (carried to next iter)
// The wave itself interleaves MFMA issue with softmax VALU (one instr/cyc
// issue, MFMA executes in background), so both pipes stay fed without
// cross-block tricks. L2 locality preserved (co-XCD blocks start together).
// Ring-slot audit @iter it: read K@it&3, V@(it-1)&3, write (it+2)&3 —
// pairwise distinct mod 4; counted vmcnt guarantees stage(it) landed.
//
// S^T = K.Q^T with key labeling key(sb,m)=32(sb&1)+8(m>>2)+4(sb>>1)+(m&3) so the
// S^T C-layout regs ARE the P B-frags for O^T = V^T.P^T (P never leaves regs).
// Partials (unnormalized bf16 O, fp32 l) written per quarter; merged by merge_y.
// NO device-scope fences/atomics in-kernel: R9 showed __threadfence() costs ~8x.
__global__ __launch_bounds__(512, 2) void attn_causal(
    const __hip_bfloat16* __restrict__ Q,
    const __hip_bfloat16* __restrict__ K,
    const __hip_bfloat16* __restrict__ Vt,
    __hip_bfloat16* __restrict__ PoB,   // [4][T*C]
    float* __restrict__ PlB,            // [4][16*T]
    int T, int C)
{
    // XCD-aware remap: lin -> (xcd chunk) so heads pair up per XCD.
    const int nwg  = (int)(gridDim.x * gridDim.y);      // 512
    const int chunk = nwg >> 3;                          // 64 (nwg % 8 == 0)
    const int lin  = (int)(blockIdx.x + gridDim.x * blockIdx.y);
    const int work = (lin & 7) * chunk + (lin >> 3);
    const int h  = work >> 5;           // head [0,16)
    const int bx = work & 31;           // [0,32)
    const int j  = bx & 7;              // pair index
    const int sq = bx >> 3;             // quarter [0,4)
    const int tid  = threadIdx.x;
    const int w    = tid >> 6;          // wave [0,8)
    const int lane = tid & 63;
    const int l15  = lane & 15;
    const int quad = lane >> 4;

    const size_t TCs = (size_t)T * C;
    const size_t HT  = (size_t)T * 16;
    __hip_bfloat16* Po = PoB + (size_t)sq * TCs;
    float* Pl = PlB + (size_t)sq * HT;

    const int len1 = j + 1, len2 = 16 - j;
    const int tile1 = j,    tile2 = 15 - j;
    const int kb1 = len1 * sq, kb2 = len2 * sq;   // quarter starts

    __shared__ __align__(16) __hip_bfloat16 Ks[4][64 * 64];
    __shared__ __align__(16) __hip_bfloat16 Vts[4][64 * 64];

    const int r0 = tid >> 3, g0 = ((tid & 7) ^ (r0 & 7)) * 8;
    const __hip_bfloat16* Kg0 = K + (size_t)sig(r0) * C + h * 64 + g0;
    const __hip_bfloat16* Vg0 = Vt + (size_t)(h * 64 + r0) * T + g0;

    int koff[2][4], voff[2][4];
    #pragma unroll
    for (int kd = 0; kd < 2; ++kd)
        #pragma unroll
        for (int sb = 0; sb < 4; ++sb) {
            const int kappa = 32 * (sb & 1) + 8 * (l15 >> 2) + 4 * (sb >> 1) + (l15 & 3);
            const int rho = sig(kappa);
            koff[kd][sb] = rho * 64 + (((kd * 4 + quad) ^ (rho & 7)) << 3);
        }
    #pragma unroll
    for (int kk = 0; kk < 2; ++kk)
        #pragma unroll
        for (int db = 0; db < 4; ++db) {
            const int vrow = db * 16 + l15;
            voff[kk][db] = vrow * 64 + (((kk * 4 + quad) ^ (vrow & 7)) << 3);
        }

    bf16x8 ones;
    #pragma unroll
    for (int jj = 0; jj < 8; ++jj) ones[jj] = (__bf16)1.0f;

    int qbase = tile1 * 256 + w * 32;
    // aq loads issued BEFORE the stages: vmcnt retires in order, so the
    // compiler's wait-for-aq never forces the (newer) prefetch to drain.
    bf16x8 aq[2][2];
    #pragma unroll
    for (int rb = 0; rb < 2; ++rb)
        #pragma unroll
        for (int kd = 0; kd < 2; ++kd)
            aq[rb][kd] = *(const bf16x8*)(
                Q + (size_t)(qbase + rb * 16 + l15) * C + h * 64 + kd * 32 + quad * 8);

    f32x4 o[2][4] = {};
    f32x4 lacc[2] = {};
    bf16x8 bp[2][2];
    bool livePrev = false;

    // stage K/V chunk for flattened index idx into ring slot idx&3 (2 loads)
    auto stage = [&](int idx) {
        const int kb = (idx < len1) ? (kb1 + idx) : (kb2 + idx - len1);
        const size_t so = (size_t)kb << 6;
        const int sl = idx & 3;
        async_load16(Kg0 + so * C, &Ks[sl][tid * 8]);
        async_load16(Vg0 + so, &Vts[sl][tid * 8]);
    };

    stage(0);
    stage(1);

    for (int it = 0; it < 17; ++it) {
        if (it + 2 < 17) stage(it + 2);
        // counted-vmcnt barrier: wait only for stage(it) (oldest 2 loads),
        // leaving the 4 prefetch loads for it+1/it+2 in flight across the
        // barrier. Every wave does the same wait before s_barrier, so after
        // the barrier slot it&3 is fully populated by all 512 threads.
        if (it < 15)
            asm volatile("s_waitcnt vmcnt(4)\n\ts_barrier" ::: "memory");
        else if (it == 15)
            asm volatile("s_waitcnt vmcnt(2)\n\ts_barrier" ::: "memory");
        else
            asm volatile("s_waitcnt vmcnt(0)\n\ts_barrier" ::: "memory");

        // ---- deferred PV(it-1): independent MFMAs fill the pipe while this
        // iteration's QK and softmax are still forming ----
        if (livePrev) {
            const int sp = (it - 1) & 3;
            lacc[0] = MFMA_BF16(ones, bp[0][0], lacc[0], 0, 0, 0);
            lacc[0] = MFMA_BF16(ones, bp[0][1], lacc[0], 0, 0, 0);
            lacc[1] = MFMA_BF16(ones, bp[1][0], lacc[1], 0, 0, 0);
            lacc[1] = MFMA_BF16(ones, bp[1][1], lacc[1], 0, 0, 0);
            #pragma unroll
            for (int kk = 0; kk < 2; ++kk)
                #pragma unroll
                for (int db = 0; db < 4; ++db) {
                    bf16x8 av = *(const bf16x8*)(&Vts[sp][voff[kk][db]]);
                    o[0][db] = MFMA_BF16(av, bp[0][kk], o[0][db], 0, 0, 0);
                    o[1][db] = MFMA_BF16(av, bp[1][kk], o[1][db], 0, 0, 0);
                }
        }

        if (it == len1) {
            // flush phase-1 partials (complete: PV(len1-1) just applied),
            // switch to tile2
            #pragma unroll
            for (int rb = 0; rb < 2; ++rb) {
                const int row = qbase + rb * 16 + l15;
                #pragma unroll
                for (int db = 0; db < 4; ++db) {
                    __hip_bfloat16 t[4];
                    #pragma unroll
                    for (int r = 0; r < 4; ++r)
                        t[r] = __float2bfloat16(o[rb][db][r]);
                    *(bf16x4*)(Po + (size_t)row * C + h * 64 + db * 16 + quad * 4)
                        = *(const bf16x4*)t;
                    o[rb][db] = (f32x4){0.f, 0.f, 0.f, 0.f};
                }
                if (quad == 0)
                    Pl[(size_t)h * T + row] = lacc[rb][0];
                lacc[rb] = (f32x4){0.f, 0.f, 0.f, 0.f};
            }
            qbase = tile2 * 256 + w * 32;
            #pragma unroll
            for (int rb = 0; rb < 2; ++rb)
                #pragma unroll
                for (int kd = 0; kd < 2; ++kd)
                    aq[rb][kd] = *(const bf16x8*)(
                        Q + (size_t)(qbase + rb * 16 + l15) * C + h * 64 + kd * 32 + quad * 8);
        }

        const int cur = it & 3;
        const int kb = (it < len1) ? (kb1 + it) : (kb2 + it - len1);
        const int s0 = kb << 6;
        const bool live = (s0 <= qbase + 31);   // wave-uniform

        if (live) {
            // ---- QK^T(it): sv = K . Q^T ----
            f32x4 sv[2][4] = {};
            #pragma unroll
            for (int kd = 0; kd < 2; ++kd)
                #pragma unroll
                for (int sb = 0; sb < 4; ++sb) {
                    bf16x8 ak = *(const bf16x8*)(&Ks[cur][koff[kd][sb]]);
                    sv[0][sb] = MFMA_BF16(ak, aq[0][kd], sv[0][sb], 0, 0, 0);
                    sv[1][sb] = MFMA_BF16(ak, aq[1][kd], sv[1][sb], 0, 0, 0);
                }

            // ---- softmax(it) -> bp (consumed by PV at iter it+1) ----
            const bool diag = (s0 + 63 > qbase);  // wave-uniform
            #pragma unroll
            for (int rb = 0; rb < 2; ++rb) {
                float pv[4][4];
                #pragma unroll
                for (int sb = 0; sb < 4; ++sb)
                    #pragma unroll
                    for (int r = 0; r < 4; ++r)
                        pv[sb][r] = __builtin_amdgcn_exp2f(sv[rb][sb][r]);
                if (diag) {
                    const int thr = qbase + rb * 16 + l15 - s0 - 8 * quad;
                    #pragma unroll
                    for (int sb = 0; sb < 4; ++sb)
                        #pragma unroll
                        for (int r = 0; r < 4; ++r) {
                            const int c = 32 * (sb & 1) + 4 * (sb >> 1) + r;
                            pv[sb][r] = (c <= thr) ? pv[sb][r] : 0.f;
                        }
                }
                #pragma unroll
                for (int kk = 0; kk < 2; ++kk) {
                    union { unsigned int u[4]; bf16x8 v; } pk;
                    pk.u[0] = pack_bf16_trunc(pv[kk][0], pv[kk][1]);
                    pk.u[1] = pack_bf16_trunc(pv[kk][2], pv[kk][3]);
                    pk.u[2] = pack_bf16_trunc(pv[kk + 2][0], pv[kk + 2][1]);
                    pk.u[3] = pack_bf16_trunc(pv[kk + 2][2], pv[kk + 2][3]);
                    bp[rb][kk] = pk.v;
                }
            }
        }
        livePrev = live;
    }

    // ---- drain the pipeline: PV(16) ----
    if (livePrev) {
        const int sp = 16 & 3;
        lacc[0] = MFMA_BF16(ones, bp[0][0], lacc[0], 0, 0, 0);
        lacc[0] = MFMA_BF16(ones, bp[0][1], lacc[0], 0, 0, 0);
        lacc[1] = MFMA_BF16(ones, bp[1][0], lacc[1], 0, 0, 0);
        lacc[1] = MFMA_BF16(ones, bp[1][1], lacc[1], 0, 0, 0);
        #pragma unroll
        for (int kk = 0; kk < 2; ++kk)
            #pragma unroll
            for (int db = 0; db < 4; ++db) {
                bf16x8 av = *(const bf16x8*)(&Vts[sp][voff[kk][db]]);
                o[0][db] = MFMA_BF16(av, bp[0][kk], o[0][db], 0, 0, 0);
                o[1][db] = MFMA_BF16(av, bp[1][kk], o[1][db], 0, 0, 0);
            }
    }

    // final flush (tile2)
    #pragma unroll
    for (int rb = 0; rb < 2; ++rb) {
        const int row = qbase + rb * 16 + l15;
        #pragma unroll
        for (int db = 0; db < 4; ++db) {
            __hip_bfloat16 t[4];
            #pragma unroll
            for (int r = 0; r < 4; ++r)
                t[r] = __float2bfloat16(o[rb][db][r]);
            *(bf16x4*)(Po + (size_t)row * C + h * 64 + db * 16 + quad * 4)
                = *(const bf16x4*)t;
        }
        if (quad == 0)
            Pl[(size_t)h * T + row] = lacc[rb][0];
    }
}

// Y = (sum_z Po[z]) / (sum_z Pl[z]), bf16 out. 8 elems/thread.
__global__ __launch_bounds__(256) void merge_y(
    const __hip_bfloat16* __restrict__ PoB, const float* __restrict__ PlB,
    __hip_bfloat16* __restrict__ Y, int T, int C)
{
    const size_t i = ((size_t)blockIdx.x * 256 + threadIdx.x) * 8;
    const int row = (int)(i / C);
    const int h   = ((int)(i % C)) >> 6;
    const size_t TC = (size_t)T * C;
    const size_t HT = (size_t)T * 16;
    float acc[8] = {};
    float l = 0.f;
    #pragma unroll
    for (int z = 0; z < 4; ++z) {
        bf16x8 a = *(const bf16x8*)(PoB + z * TC + i);
        #pragma unroll
        for (int r = 0; r < 8; ++r)
            acc[r] += (float)(((const __bf16*)&a)[r]);
        l += PlB[z * HT + (size_t)h * T + row];
    }
    const float inv = 1.0f / l;
    __hip_bfloat16 t[8];
    #pragma unroll
    for (int r = 0; r < 8; ++r)
        t[r] = __float2bfloat16(acc[r] * inv);
    *(bf16x8*)(Y + i) = *(const bf16x8*)t;
}

extern "C" void kernel_launch(void* const* d_in, const int* in_sizes, int n_in,
                              void* d_out, int out_size, void* d_ws, size_t ws_size,
                              hipStream_t stream)
{
    const float* x  = (const float*)d_in[0];
    const float* Wq = (const float*)d_in[1];
    const float* bq = (const float*)d_in[2];
    const float* Wk = (const float*)d_in[3];
    const float* bk = (const float*)d_in[4];
    const float* Wv = (const float*)d_in[5];
    const float* bv = (const float*)d_in[6];
    const float* Wp = (const float*)d_in[7];
    const float* bp = (const float*)d_in[8];

    const int C = 1024;
    const int T = in_sizes[0] / C;   // 4096
    const int H = 16;
    const size_t TC = (size_t)T * C;
    const size_t CC = (size_t)C * C;

    // ws (bf16 elems): xb | W4 | Q | K | Vt | Po[4] | Pl[4] (f32)
    __hip_bfloat16* xb  = (__hip_bfloat16*)d_ws;
    __hip_bfloat16* Wqb = xb + TC;
    __hip_bfloat16* Wkb = Wqb + CC;
    __hip_bfloat16* Wvb = Wkb + CC;
    __hip_bfloat16* Wpb = Wvb + CC;
    __hip_bfloat16* Qw  = Wpb + CC;
    __hip_bfloat16* Kw  = Qw + TC;
    __hip_bfloat16* Vtw = Kw + TC;
    __hip_bfloat16* PoB = Vtw + TC;          // 4 * TC bf16
    float* PlB = (float*)(PoB + 4 * TC);     // 4 * 16*T fp32
    __hip_bfloat16* Yw  = xb;                // alias: x dead after QKV GEMM
    float* out = (float*)d_out;

    convert_all<<<(int)(TC / 2048 + 4 * CC / 2048), 256, 0, stream>>>(
        x, Wq, Wk, Wv, Wp, xb, Wqb, Wkb, Wvb, Wpb, (int)TC, (int)CC);

    gemm_qkv<<<dim3(T / 128, 3072 / 128), 512, 0, stream>>>(
        xb, Wqb, bq, bk, bv, Qw, Kw, Vtw, T, C);

    attn_causal<<<dim3(32, H), 512, 0, stream>>>(
        Qw, Kw, Vtw, PoB, PlB, T, C);

    merge_y<<<(int)(TC / 8 / 256), 256, 0, stream>>>(
        PoB, PlB, Yw, T, C);

    gemm_out_f32<<<dim3(T / 64, C / 128), 256, 0, stream>>>(
        Yw, Wpb, bp, out, T, C, C);
}